// Round 3
// baseline (416.016 us; speedup 1.0000x reference)
//
#include <hip/hip_runtime.h>
#include <math.h>

// Problem constants
#define B_   32
#define CD   1280     // C
#define HW_  1024
#define TD_  768
#define LD_  64
#define EPSF 1e-5f
#define LORA_SCALE_F 0.125f   // 64^-0.5

// ---------- reduction helpers ----------
__device__ __forceinline__ float wredSum(float a) {
#pragma unroll
  for (int o = 32; o; o >>= 1) a += __shfl_xor(a, o, 64);
  return a;
}
__device__ __forceinline__ void wred2(float& a, float& b) {
#pragma unroll
  for (int o = 32; o; o >>= 1) { a += __shfl_xor(a, o, 64); b += __shfl_xor(b, o, 64); }
}
__device__ __forceinline__ void wred3(float& a, float& b, float& c) {
#pragma unroll
  for (int o = 32; o; o >>= 1) {
    a += __shfl_xor(a, o, 64); b += __shfl_xor(b, o, 64); c += __shfl_xor(c, o, 64);
  }
}
// N accumulators, one 6-step butterfly, all-lanes result. Static indices only.
template<int N>
__device__ __forceinline__ void wredN(float* v) {
#pragma unroll
  for (int o = 32; o; o >>= 1) {
#pragma unroll
    for (int k = 0; k < N; k++) v[k] += __shfl_xor(v[k], o, 64);
  }
}
__device__ __forceinline__ void blockSum2(float& a, float& b, float2* red) {
  int t = threadIdx.x;
  red[t] = make_float2(a, b); __syncthreads();
#pragma unroll
  for (int s = 128; s > 0; s >>= 1) {
    if (t < s) { red[t].x += red[t + s].x; red[t].y += red[t + s].y; }
    __syncthreads();
  }
  a = red[0].x; b = red[0].y; __syncthreads();
}

// ---------- A12: q[c] = to_q_w[c,:] . LN(token_q_emb)*g+b ; grid 320x256 ----------
__global__ __launch_bounds__(256) void kA12(const float* __restrict__ tq,
                                            const float* __restrict__ lng,
                                            const float* __restrict__ lnb,
                                            const float* __restrict__ to_q_w,
                                            float* __restrict__ q_out) {
  __shared__ float lnq[TD_];
  __shared__ float2 red[256];
  int t = threadIdx.x;
  float s = 0.f, ss = 0.f, vals[3];
#pragma unroll
  for (int k = 0; k < 3; k++) { float v = tq[t + 256 * k]; vals[k] = v; s += v; ss += v * v; }
  blockSum2(s, ss, red);
  float mu = s * (1.f / TD_);
  float r = rsqrtf(ss * (1.f / TD_) - mu * mu + EPSF);
#pragma unroll
  for (int k = 0; k < 3; k++) { int i = t + 256 * k; lnq[i] = (vals[k] - mu) * r * lng[i] + lnb[i]; }
  __syncthreads();
  int c = blockIdx.x * 4 + (t >> 6);
  int lane = t & 63;
  const float4* w4 = (const float4*)(to_q_w + (size_t)c * TD_);
  const float4* l4 = (const float4*)lnq;
  float dot = 0.f;
#pragma unroll
  for (int i = 0; i < 3; i++) {
    int f = i * 64 + lane;
    float4 w = w4[f], l = l4[f];
    dot += w.x * l.x + w.y * l.y + w.z * l.z + w.w * l.w;
  }
  dot = wredSum(dot);
  if (lane == 0) q_out[c] = dot;
}

// ---------- A3456: lq = lora_q_w . LN(q) (redundant per block), then
//                   w_eff[c] = sum_d lq[d]*lora_k_w[d,c] ; grid 5x256 ----------
__global__ __launch_bounds__(256) void kA3456(const float* __restrict__ q_in,
                                              const float* __restrict__ lora_q_w,
                                              const float* __restrict__ lora_k_w,
                                              float* __restrict__ w_eff) {
  __shared__ float qn[CD];
  __shared__ float lq[LD_];
  __shared__ float redS[8];
  int t = threadIdx.x;
  int wid = t >> 6, lane = t & 63;
  float s = 0.f, ss = 0.f, vals[5];
#pragma unroll
  for (int k = 0; k < 5; k++) { float v = q_in[t + 256 * k]; vals[k] = v; s += v; ss += v * v; }
  wred2(s, ss);
  if (lane == 0) { redS[wid * 2] = s; redS[wid * 2 + 1] = ss; }
  __syncthreads();
  s = redS[0] + redS[2] + redS[4] + redS[6];
  ss = redS[1] + redS[3] + redS[5] + redS[7];
  float mu = s * (1.f / CD);
  float r = rsqrtf(ss * (1.f / CD) - mu * mu + EPSF);
#pragma unroll
  for (int k = 0; k < 5; k++) { int i = t + 256 * k; qn[i] = (vals[k] - mu) * r; }
  __syncthreads();
  {
    int gg = t >> 2, sub = t & 3;
    const float4* w4 = (const float4*)(lora_q_w + (size_t)gg * CD);
    const float4* q4 = (const float4*)qn;
    float dot = 0.f;
#pragma unroll 8
    for (int i = 0; i < 80; i++) {
      int f = i * 4 + sub;
      float4 w = w4[f], qq = q4[f];
      dot += w.x * qq.x + w.y * qq.y + w.z * qq.z + w.w * qq.w;
    }
    dot += __shfl_xor(dot, 1, 64);
    dot += __shfl_xor(dot, 2, 64);
    if (sub == 0) lq[gg] = dot;
  }
  __syncthreads();
  int c = blockIdx.x * 256 + t;
  float acc = 0.f;
#pragma unroll 8
  for (int d = 0; d < LD_; d++) acc += lq[d] * lora_k_w[(size_t)d * CD + c];
  w_eff[c] = acc;
}

// ---------- BD1 merged, role-interleaved:
//   blockIdx%5 != 4 (2048 blocks): sim[row] via single-pass 7-moment expansion
//   blockIdx%5 == 4 ( 512 blocks): per-column (b,j) stats of infeat
__global__ __launch_bounds__(256, 4) void kBD1(const float* __restrict__ kin,
                                               const float* __restrict__ g,
                                               const float* __restrict__ bb,
                                               const float* __restrict__ w_eff,
                                               float* __restrict__ sim,
                                               const float* __restrict__ infeat,
                                               float* __restrict__ mu_out,
                                               float* __restrict__ r_out) {
  __shared__ float smem[5152];   // kB: 4x1280 coef SoA + 32 red | kD1: 2048 floats reused
  int t = threadIdx.x;
  int m5 = blockIdx.x % 5, d5 = blockIdx.x / 5;
  int wid = t >> 6, lane = t & 63;
  if (m5 != 4) {
    // ---- kB body: 2048 logical blocks, 4 rows per wave ----
    int kbid = d5 * 4 + m5;           // [0,2048)
    float* cg  = smem;                // g
    float* cg2 = smem + 1280;         // g^2
    float* cgb = smem + 2560;         // g*b
    float* cwg = smem + 3840;         // w*g
    float* red = smem + 5120;         // 32
    // stage coefficients + per-block scalar sums (one wred8, one barrier)
    float p[8] = {0.f,0.f,0.f,0.f,0.f,0.f,0.f,0.f};
    for (int kk = t; kk < 320; kk += 256) {
      float4 g4 = ((const float4*)g)[kk];
      float4 b4 = ((const float4*)bb)[kk];
      float4 w4 = ((const float4*)w_eff)[kk];
      float4 q4  = make_float4(g4.x*g4.x, g4.y*g4.y, g4.z*g4.z, g4.w*g4.w);
      float4 gb4 = make_float4(g4.x*b4.x, g4.y*b4.y, g4.z*b4.z, g4.w*b4.w);
      float4 wg4 = make_float4(w4.x*g4.x, w4.y*g4.y, w4.z*g4.z, w4.w*g4.w);
      ((float4*)cg)[kk]  = g4;
      ((float4*)cg2)[kk] = q4;
      ((float4*)cgb)[kk] = gb4;
      ((float4*)cwg)[kk] = wg4;
      p[0] += g4.x + g4.y + g4.z + g4.w;                    // G0
      p[1] += b4.x + b4.y + b4.z + b4.w;                    // B0
      p[2] += q4.x + q4.y + q4.z + q4.w;                    // G2
      p[3] += gb4.x + gb4.y + gb4.z + gb4.w;                // GB
      p[4] += b4.x*b4.x + b4.y*b4.y + b4.z*b4.z + b4.w*b4.w;// B2
      p[5] += wg4.x + wg4.y + wg4.z + wg4.w;                // WG
      p[6] += w4.x*b4.x + w4.y*b4.y + w4.z*b4.z + w4.w*b4.w;// WB
      p[7] += w4.x + w4.y + w4.z + w4.w;                    // W0
    }
    wredN<8>(p);
    if (lane == 0) {
#pragma unroll
      for (int j = 0; j < 8; j++) red[wid * 8 + j] = p[j];
    }
    __syncthreads();
    float G0 = red[0] + red[8]  + red[16] + red[24];
    float B0 = red[1] + red[9]  + red[17] + red[25];
    float G2 = red[2] + red[10] + red[18] + red[26];
    float GB = red[3] + red[11] + red[19] + red[27];
    float B2 = red[4] + red[12] + red[20] + red[28];
    float WG = red[5] + red[13] + red[21] + red[29];
    float WB = red[6] + red[14] + red[22] + red[30];
    float W0 = red[7] + red[15] + red[23] + red[31];
    const float invC = 1.f / CD;
    const float4* cg4  = (const float4*)cg;
    const float4* cg24 = (const float4*)cg2;
    const float4* cgb4 = (const float4*)cgb;
    const float4* cwg4 = (const float4*)cwg;

    int gw = kbid * 4 + wid;          // [0,8192)
#pragma unroll
    for (int m = 0; m < 2; m++) {
      int rowA = gw + 16384 * m;
      int rowB = rowA + 8192;
      const float4* xA = (const float4*)(kin + (size_t)rowA * CD);
      const float4* xB = (const float4*)(kin + (size_t)rowB * CD);
      // v[0..6] rowA: S,SS,Gx,G2x,G2x2,GBx,WGx ; v[7..13] rowB
      float v[14];
#pragma unroll
      for (int k = 0; k < 14; k++) v[k] = 0.f;
#pragma unroll
      for (int i = 0; i < 5; i++) {
        int f = i * 64 + lane;
        float4 xa = xA[f], xb = xB[f];
        float4 c1 = cg4[f], c2 = cg24[f], c3 = cgb4[f], c4 = cwg4[f];
#define ACC(X, Gc, G2c, GBc, WGc, o) { \
        float x_ = (X); float x2_ = x_ * x_; \
        v[(o)+0] += x_; v[(o)+1] += x2_; \
        v[(o)+2] = fmaf((Gc),  x_,  v[(o)+2]); \
        v[(o)+3] = fmaf((G2c), x_,  v[(o)+3]); \
        v[(o)+4] = fmaf((G2c), x2_, v[(o)+4]); \
        v[(o)+5] = fmaf((GBc), x_,  v[(o)+5]); \
        v[(o)+6] = fmaf((WGc), x_,  v[(o)+6]); }
        ACC(xa.x, c1.x, c2.x, c3.x, c4.x, 0)
        ACC(xa.y, c1.y, c2.y, c3.y, c4.y, 0)
        ACC(xa.z, c1.z, c2.z, c3.z, c4.z, 0)
        ACC(xa.w, c1.w, c2.w, c3.w, c4.w, 0)
        ACC(xb.x, c1.x, c2.x, c3.x, c4.x, 7)
        ACC(xb.y, c1.y, c2.y, c3.y, c4.y, 7)
        ACC(xb.z, c1.z, c2.z, c3.z, c4.z, 7)
        ACC(xb.w, c1.w, c2.w, c3.w, c4.w, 7)
#undef ACC
      }
      wredN<14>(v);
      // rowA finish
      float mu1a = v[0] * invC;
      float r1a  = rsqrtf(v[1] * invC - mu1a * mu1a + EPSF);
      float s2a  = r1a * (v[2] - mu1a * G0) + B0;
      float mu2a = s2a * invC;
      float ss2a = r1a * r1a * (v[4] - 2.f * mu1a * v[3] + mu1a * mu1a * G2)
                 + 2.f * r1a * (v[5] - mu1a * GB) + B2;
      float r2a  = rsqrtf(ss2a * invC - mu2a * mu2a + EPSF);
      float dta  = r1a * (v[6] - mu1a * WG) + WB;
      float simA = LORA_SCALE_F * r2a * (dta - mu2a * W0);
      // rowB finish
      float mu1b = v[7] * invC;
      float r1b  = rsqrtf(v[8] * invC - mu1b * mu1b + EPSF);
      float s2b  = r1b * (v[9] - mu1b * G0) + B0;
      float mu2b = s2b * invC;
      float ss2b = r1b * r1b * (v[11] - 2.f * mu1b * v[10] + mu1b * mu1b * G2)
                 + 2.f * r1b * (v[12] - mu1b * GB) + B2;
      float r2b  = rsqrtf(ss2b * invC - mu2b * mu2b + EPSF);
      float dtb  = r1b * (v[13] - mu1b * WG) + WB;
      float simB = LORA_SCALE_F * r2b * (dtb - mu2b * W0);
      if (lane == 0) { sim[rowA] = simA; sim[rowB] = simB; }
    }
  } else {
    // ---- kD1 body: 512 logical blocks ----
    int blk = d5;                     // [0,512)
    int tile = blk & 15, b = blk >> 4;
    int jg = t & 15;      // 16 float4 groups -> 64 columns
    int slice = t >> 4;   // 16 c-slices of 80
    int j0 = tile * 64 + jg * 4;
    const float* base = infeat + (size_t)b * CD * HW_ + j0;
    float4 s = make_float4(0, 0, 0, 0), q = make_float4(0, 0, 0, 0);
    int c0 = slice * 80;
#pragma unroll 8
    for (int c = c0; c < c0 + 80; c++) {
      float4 v = *(const float4*)(base + (size_t)c * HW_);
      s.x += v.x; s.y += v.y; s.z += v.z; s.w += v.w;
      q.x += v.x * v.x; q.y += v.y * v.y; q.z += v.z * v.z; q.w += v.w * v.w;
    }
    float4* sArr = (float4*)smem;          // [16][16]
    float4* qArr = ((float4*)smem) + 256;  // [16][16]
    sArr[slice * 16 + jg] = s; qArr[slice * 16 + jg] = q;
    __syncthreads();
#pragma unroll
    for (int st = 8; st > 0; st >>= 1) {
      if (slice < st) {
        float4 a = sArr[slice * 16 + jg], b2 = sArr[(slice + st) * 16 + jg];
        a.x += b2.x; a.y += b2.y; a.z += b2.z; a.w += b2.w;
        sArr[slice * 16 + jg] = a;
        a = qArr[slice * 16 + jg]; b2 = qArr[(slice + st) * 16 + jg];
        a.x += b2.x; a.y += b2.y; a.z += b2.z; a.w += b2.w;
        qArr[slice * 16 + jg] = a;
      }
      __syncthreads();
    }
    if (slice == 0) {
      float4 S = sArr[jg], Q = qArr[jg], mu, r;
      mu.x = S.x * (1.f / CD); mu.y = S.y * (1.f / CD);
      mu.z = S.z * (1.f / CD); mu.w = S.w * (1.f / CD);
      r.x = rsqrtf(Q.x * (1.f / CD) - mu.x * mu.x + EPSF);
      r.y = rsqrtf(Q.y * (1.f / CD) - mu.y * mu.y + EPSF);
      r.z = rsqrtf(Q.z * (1.f / CD) - mu.z * mu.z + EPSF);
      r.w = rsqrtf(Q.w * (1.f / CD) - mu.w * mu.w + EPSF);
      int j = b * HW_ + j0;
      *(float4*)(mu_out + j) = mu;
      *(float4*)(r_out + j) = r;
    }
  }
}

// ---------- D2f: softmax prologue (folded kC) + weighted row dots,
//            8 columns batched into ONE wred16 ; grid 1280x256 ----------
__global__ __launch_bounds__(256, 4) void kD2f(const float* __restrict__ infeat,
                                               const float* __restrict__ sim,
                                               const float* __restrict__ mask,
                                               const float* __restrict__ mu,
                                               const float* __restrict__ r,
                                               const float* __restrict__ g,
                                               const float* __restrict__ bb,
                                               float* __restrict__ out) {
  __shared__ float4 w1s[HW_ / 4], w2s[HW_ / 4];  // 8 KB
  __shared__ float red[16];
  int t = threadIdx.x;
  int b = blockIdx.x / 40, tile = blockIdx.x % 40;
  int wid = t >> 6, lane = t & 63;

  // ----- softmax + weight-fold prologue -----
  float4 sv = ((const float4*)(sim + b * HW_))[t];
  float4 mv = ((const float4*)(mask + b * HW_))[t];
  float4 muv = ((const float4*)(mu + b * HW_))[t];
  float4 rv = ((const float4*)(r + b * HW_))[t];
  const float NEG = -3.4028235e38f;
  float se0 = mv.x > 0.f ? sv.x : NEG;
  float se1 = mv.y > 0.f ? sv.y : NEG;
  float se2 = mv.z > 0.f ? sv.z : NEG;
  float se3 = mv.w > 0.f ? sv.w : NEG;
  float m = fmaxf(fmaxf(se0, se1), fmaxf(se2, se3));
#pragma unroll
  for (int o = 32; o; o >>= 1) m = fmaxf(m, __shfl_xor(m, o, 64));
  if (lane == 0) red[wid] = m;
  __syncthreads();
  float M = fmaxf(fmaxf(red[0], red[1]), fmaxf(red[2], red[3]));
  float e0 = expf(se0 - M), e1 = expf(se1 - M), e2 = expf(se2 - M), e3 = expf(se3 - M);
  float Z = e0 + e1 + e2 + e3;
  float t1 = e0 * rv.x * muv.x + e1 * rv.y * muv.y + e2 * rv.z * muv.z + e3 * rv.w * muv.w;
  float t3 = rv.x * muv.x + rv.y * muv.y + rv.z * muv.z + rv.w * muv.w;
  wred3(Z, t1, t3);
  __syncthreads();   // protect red[] reuse
  if (lane == 0) { red[4 + wid * 3] = Z; red[5 + wid * 3] = t1; red[6 + wid * 3] = t3; }
  __syncthreads();
  Z  = red[4] + red[7] + red[10] + red[13];
  t1 = red[5] + red[8] + red[11] + red[14];
  t3 = red[6] + red[9] + red[12] + red[15];
  float inv = 1.f / Z;
  float s1 = t1 * inv;              // S1 = sum attn*r*mu
  float s3 = t3 * (1.f / HW_);      // S3 = sum (r/HW)*mu
  w1s[t] = make_float4(e0 * rv.x * inv, e1 * rv.y * inv, e2 * rv.z * inv, e3 * rv.w * inv);
  w2s[t] = make_float4(rv.x * (1.f / HW_), rv.y * (1.f / HW_),
                       rv.z * (1.f / HW_), rv.w * (1.f / HW_));
  __syncthreads();

  // ----- main weighted-dot loop: 8 columns, one butterfly -----
  int cbase = tile * 32 + wid * 8;
  const float* bbase = infeat + (size_t)b * CD * HW_;
  float v[16];   // v[2k]=d1(col k), v[2k+1]=d2(col k)
#pragma unroll
  for (int k = 0; k < 16; k++) v[k] = 0.f;
#pragma unroll
  for (int i = 0; i < 4; i++) {
    int f = i * 64 + lane;
    float4 a = w1s[f], w = w2s[f];
#pragma unroll
    for (int k = 0; k < 8; k++) {
      float4 x = ((const float4*)(bbase + (size_t)(cbase + k) * HW_))[f];
      v[2 * k]     += x.x * a.x + x.y * a.y + x.z * a.z + x.w * a.w;
      v[2 * k + 1] += x.x * w.x + x.y * w.y + x.z * w.z + x.w * w.w;
    }
  }
  wredN<16>(v);
  if (lane == 0) {
#pragma unroll
    for (int k = 0; k < 8; k++) {
      int c = cbase + k;
      float gc = g[c], bc = bb[c];
      float fg = gc * (v[2 * k] - s1) + bc;
      float vm = gc * (v[2 * k + 1] - s3) + bc;
      out[(size_t)b * (2 * CD) + c] = fg;
      out[(size_t)b * (2 * CD) + CD + c] = vm - fg;
    }
  }
}

extern "C" void kernel_launch(void* const* d_in, const int* in_sizes, int n_in,
                              void* d_out, int out_size, void* d_ws, size_t ws_size,
                              hipStream_t stream) {
  const float* infeat  = (const float*)d_in[0];
  const float* inquery = (const float*)d_in[1];
  const float* tq      = (const float*)d_in[2];
  const float* to_q_w  = (const float*)d_in[3];
  const float* ln_x_g  = (const float*)d_in[4];
  const float* ln_x_b  = (const float*)d_in[5];
  const float* ln_k_g  = (const float*)d_in[6];
  const float* ln_k_b  = (const float*)d_in[7];
  const float* ln_q_g  = (const float*)d_in[8];
  const float* ln_q_b  = (const float*)d_in[9];
  const float* lora_q_w = (const float*)d_in[10];
  const float* lora_k_w = (const float*)d_in[11];
  const float* mask    = (const float*)d_in[12];
  float* out = (float*)d_out;

  float* ws = (float*)d_ws;
  float* q_ws    = ws;              // 1280
  float* weff_ws = ws + 1280;       // 1280
  float* sim_ws  = ws + 2560;       // 32768
  float* mu_ws   = ws + 35328;      // 32768
  float* r_ws    = ws + 68096;      // 32768

  kA12<<<320, 256, 0, stream>>>(tq, ln_q_g, ln_q_b, to_q_w, q_ws);
  kA3456<<<5, 256, 0, stream>>>(q_ws, lora_q_w, lora_k_w, weff_ws);
  kBD1<<<2560, 256, 0, stream>>>(inquery, ln_k_g, ln_k_b, weff_ws, sim_ws,
                                 infeat, mu_ws, r_ws);
  kD2f<<<1280, 256, 0, stream>>>(infeat, sim_ws, mask, mu_ws, r_ws,
                                 ln_x_g, ln_x_b, out);
}